// Round 10
// baseline (242.080 us; speedup 1.0000x reference)
//
#include <hip/hip_runtime.h>

#define N_NODES 100000
#define N_EDGES 3200000
#define IN_DIM 128
#define HID_DIM 64
#define OUT_DIM 2
#define N_GRAPHS 512

#define BSHIFT 6
#define NBK 1563           // ceil(100000/64) buckets of 64 nodes
#define NBB 1024           // binning blocks (4/CU wave-capped, 32 waves/CU, 1 round)
#define EPB2 3125          // edges per bin-block (1024*3125 = 3.2M exact)
#define CAPSHIFT 12        // 4096 slots per bucket = 8 XCD sub-regions x 512
#define SUBSHIFT 9         // 512-slot sub-region (per-XCD mean ~256, 16 sd slack)
#define LDS_E2 2816        // per-bucket LDS edge capacity in aggrf (8-aligned + self)
#define ZERO_ROW N_NODES   // all-zero fp8 row used for alignment padding

__device__ inline unsigned short f2bf(float f) {
    union { float f; unsigned int i; } v; v.f = f;
    unsigned int r = v.i + 0x7fffu + ((v.i >> 16) & 1u);
    return (unsigned short)(r >> 16);
}

typedef __attribute__((ext_vector_type(8))) short bf16x8;
typedef __attribute__((ext_vector_type(4))) float f32x4;
typedef __attribute__((ext_vector_type(2))) float f32x2;

// ---- pass 0: zero cnt_g/gsum/gcnt + ZERO_ROW (replaces all memsets) -----
__global__ __launch_bounds__(1024) void k_init(float* __restrict__ gsum,
                                               int* __restrict__ cnt_g,
                                               float* __restrict__ gcnt,
                                               unsigned char* __restrict__ xws) {
    int b = blockIdx.x, t = threadIdx.x;
    if (b < 32) {
        gsum[b * 1024 + t] = 0.f;                     // 32768 floats
    } else if (b < 45) {
        int j = (b - 32) * 1024 + t;
        if (j < NBK * 8) cnt_g[j] = 0;                // 12504 sub-counters
    } else {
        if (t < N_GRAPHS) gcnt[t] = 0.f;
        if (t >= 1008)
            ((int*)(xws + (size_t)ZERO_ROW * HID_DIM))[t - 1008] = 0;
    }
}

// ---- pass 1: fused hist + XCD-partitioned reservation + staged scatter ---
// R8 lessons applied: (a) LDS 58->27 KB by staging only 16-bit edge
// indices (col/row re-read in copy-out through L1/L2-resident windows) ->
// 4 blocks/CU wave-capped, grid 1024 = 32 waves/CU in ONE round (2x R8's
// latency hiding). (b) WRITE amplification (R8: 2.9x) came from cross-XCD
// false sharing of binned lines; each bucket's 4096 slots now split into 8
// sub-regions indexed by blockIdx&7 (same round-robin-dispatch assumption
// as the xcol swizzle) -> every 64B line written by ONE XCD, whose 3.2 MB
// binned share fits its 4 MB L2 -> partial lines merge before eviction.
// Within-bucket order nondeterministic (always was).
__global__ __launch_bounds__(512) void k_bin(const int* __restrict__ row,
                                             const int* __restrict__ col,
                                             int* __restrict__ cnt_g,
                                             int* __restrict__ binned) {
    __shared__ int h[NBK];             // count -> global run base
    __shared__ int lofs[NBK];          // local exclusive offsets
    __shared__ int cur[NBK];
    __shared__ int ps[512];
    __shared__ unsigned short idx16[EPB2];  // 6.25 KB staged edge indices
    int t = threadIdx.x;
    for (int i = t; i < NBK; i += 512) { h[i] = 0; cur[i] = 0; }
    __syncthreads();
    int s = blockIdx.x * EPB2;
    for (int i = t; i < EPB2; i += 512)
        atomicAdd(&h[col[s + i] >> BSHIFT], 1);
    __syncthreads();
    // block-wide exclusive scan of h[0..NBK) -> lofs (chunk-of-4 + H-S)
    {
        int b0 = t << 2;
        int loc[4];
        int run = 0;
#pragma unroll
        for (int j = 0; j < 4; j++) {
            int b = b0 + j;
            loc[j] = run;
            run += (b < NBK) ? h[b] : 0;
        }
        ps[t] = run;
        __syncthreads();
        for (int off = 1; off < 512; off <<= 1) {
            int v = (t >= off) ? ps[t - off] : 0;
            __syncthreads();
            ps[t] += v;
            __syncthreads();
        }
        int base = (t > 0) ? ps[t - 1] : 0;
#pragma unroll
        for (int j = 0; j < 4; j++) {
            int b = b0 + j;
            if (b < NBK) lofs[b] = base + loc[j];
        }
    }
    __syncthreads();
    // reserve runs in this block's XCD sub-region
    int xs = blockIdx.x & 7;
    for (int i = t; i < NBK; i += 512) {
        int hv = h[i];
        if (hv) h[i] = (i << CAPSHIFT) + (xs << SUBSHIFT)
                     + atomicAdd(&cnt_g[(i << 3) + xs], hv);
    }
    __syncthreads();
    // scatter edge INDICES into LDS, bucket-sorted (col re-read: L1-warm)
    for (int i = t; i < EPB2; i += 512) {
        int bk = col[s + i] >> BSHIFT;
        int rk = atomicAdd(&cur[bk], 1);
        idx16[lofs[bk] + rk] = (unsigned short)i;
    }
    __syncthreads();
    // coalesced copy-out: consecutive slots -> consecutive global addrs
    for (int i = t; i < EPB2; i += 512) {
        int idx = idx16[i];
        int c = col[s + idx];                  // L1/L2-resident gathers
        int r = row[s + idx];
        int bk = c >> BSHIFT;
        binned[h[bk] + (i - lofs[bk])] = ((c & 63) << 17) | r;
    }
}

// ---- xws = (x @ W_gcn) * dinv via MFMA, output fp8 e4m3 ------------------
// Block == bucket: degree hist fused (k_deg deleted), now iterating the 8
// sub-regions via a validity-test loop over 4096 slots (cnt8). Hist global
// loads + LDS atomics issue BEFORE the MFMA loop and complete under it.
// cnt spills to degs[] for k_aggrf. Wave does a 16-node x 64-col tile with
// mfma_f32_16x16x32_bf16; C/D: col=lane&15, row=quad*4+reg.
__global__ __launch_bounds__(256) void k_gemm(const float* __restrict__ x,
                                              const float* __restrict__ Wg,
                                              const int* __restrict__ cnt_g,
                                              const int* __restrict__ binned,
                                              int* __restrict__ degs,
                                              unsigned char* __restrict__ xws) {
    __shared__ unsigned short wb[16][64][8];   // [ks*4+nt][lane][j]  16 KB
    __shared__ int cnt[64];
    __shared__ int cnt8[8];

    int bkt = blockIdx.x;
    if (threadIdx.x < 64) cnt[threadIdx.x] = 0;
    if (threadIdx.x < 8) cnt8[threadIdx.x] = cnt_g[(bkt << 3) + threadIdx.x];
    for (int idx = threadIdx.x; idx < 1024; idx += 256) {
        int f = idx >> 6, l = idx & 63;
        int ks = f >> 2, nt = f & 3;
        int n = (l & 15) + (nt << 4);
        int kbase = (ks << 5) + ((l >> 4) << 3);
        unsigned short tmp[8];
#pragma unroll
        for (int j = 0; j < 8; j++)
            tmp[j] = f2bf(Wg[(kbase + j) * HID_DIM + n]);
        *(bf16x8*)&wb[f][l][0] = *(const bf16x8*)tmp;
    }
    __syncthreads();

    for (int i = threadIdx.x; i < (1 << CAPSHIFT); i += 256)   // deg hist
        if ((i & ((1 << SUBSHIFT) - 1)) < cnt8[i >> SUBSHIFT]) // (overlaps MFMA)
            atomicAdd(&cnt[binned[(bkt << CAPSHIFT) + i] >> 17], 1);

    int wave = threadIdx.x >> 6;
    int lane = threadIdx.x & 63;
    int q = lane >> 4, nn = lane & 15;

    bf16x8 bfrag[4][4];
#pragma unroll
    for (int ks = 0; ks < 4; ks++)
#pragma unroll
        for (int nt = 0; nt < 4; nt++)
            bfrag[ks][nt] = *(const bf16x8*)&wb[ks * 4 + nt][lane][0];

    int node0 = bkt * 64 + wave * 16;
    int arow = node0 + nn;
    if (arow > N_NODES - 1) arow = N_NODES - 1;   // clamp (stores predicated)
    const float* xrow = x + (size_t)arow * IN_DIM + (q << 3);

    f32x4 acc[4] = {{0.f,0.f,0.f,0.f},{0.f,0.f,0.f,0.f},
                    {0.f,0.f,0.f,0.f},{0.f,0.f,0.f,0.f}};
#pragma unroll
    for (int ks = 0; ks < 4; ks++) {
        float4 xa = *(const float4*)(xrow + ks * 32);
        float4 xb_ = *(const float4*)(xrow + ks * 32 + 4);
        bf16x8 af;
        af[0] = (short)f2bf(xa.x); af[1] = (short)f2bf(xa.y);
        af[2] = (short)f2bf(xa.z); af[3] = (short)f2bf(xa.w);
        af[4] = (short)f2bf(xb_.x); af[5] = (short)f2bf(xb_.y);
        af[6] = (short)f2bf(xb_.z); af[7] = (short)f2bf(xb_.w);
#pragma unroll
        for (int nt = 0; nt < 4; nt++)
            acc[nt] = __builtin_amdgcn_mfma_f32_16x16x32_bf16(af, bfrag[ks][nt], acc[nt], 0, 0, 0);
    }
    __syncthreads();                                    // cnt hist complete

    if (threadIdx.x < 64) degs[bkt * 64 + threadIdx.x] = cnt[threadIdx.x];

#pragma unroll
    for (int r = 0; r < 4; r++) {
        int lrow = wave * 16 + q * 4 + r;
        int mrow = bkt * 64 + lrow;
        if (mrow < N_NODES) {
            float dn = rsqrtf((float)cnt[lrow] + 1.0f);
            int p01 = __builtin_amdgcn_cvt_pk_fp8_f32(acc[0][r] * dn, acc[1][r] * dn, 0, false);
            int p23 = __builtin_amdgcn_cvt_pk_fp8_f32(acc[2][r] * dn, acc[3][r] * dn, 0, false);
            unsigned char* rp = xws + (size_t)mrow * HID_DIM + nn;
            rp[0]  = (unsigned char)(p01 & 0xff);
            rp[16] = (unsigned char)((p01 >> 8) & 0xff);
            rp[32] = (unsigned char)(p23 & 0xff);
            rp[48] = (unsigned char)((p23 >> 8) & 0xff);
        }
    }
}

// ---- fused local-CSR build + gather-aggregate + ReLU + mean-pool ---------
// 512-thread block per 64-node bucket. Degrees come from degs[] (k_gemm).
// CSR scatter iterates the 8 sub-regions via validity-test loop (cnt8).
// srt holds BYTE offsets (row<<6). Subset-per-node gather: each 16-lane
// subset owns ONE node end-to-end -> zero-shuffle epilogue. Lists
// 8-aligned with self-loop folded in; 8 slots/iter (2x ds_read_b128 + 8
// row-loads in flight) with 4 independent accumulator chains. Per-graph
// node counts (gcnt) accumulated here so k_mlp needs no binary search.
__global__ __launch_bounds__(512) void k_aggrf(const unsigned char* __restrict__ xws,
                                               const int* __restrict__ binned,
                                               const int* __restrict__ cnt_g,
                                               const int* __restrict__ degs,
                                               const int* __restrict__ batch,
                                               const float* __restrict__ bg,
                                               float* __restrict__ gsum,
                                               float* __restrict__ gcnt) {
    int bkt = blockIdx.x;
    int nbase = bkt << BSHIFT;
    int nnodes = N_NODES - nbase; if (nnodes > 64) nnodes = 64;
    int base = bkt << CAPSHIFT;

    __shared__ int cnt[64];
    __shared__ int lptr[65];
    __shared__ int cur[64];
    __shared__ int sb[64];
    __shared__ int cnt8[8];
    __shared__ float gcl[8];
    __shared__ alignas(16) int srt[LDS_E2];
    __shared__ float pool[8][4][64];   // [wave][graph-slot][col]

    if (threadIdx.x < 64) {
        int n = nbase + threadIdx.x;
        cnt[threadIdx.x] = (threadIdx.x < nnodes) ? degs[bkt * 64 + threadIdx.x] : 0;
        sb[threadIdx.x]  = (threadIdx.x < nnodes) ? batch[n] : 0;
        cur[threadIdx.x] = 0;
    }
    if (threadIdx.x < 8) {
        gcl[threadIdx.x] = 0.f;
        cnt8[threadIdx.x] = cnt_g[(bkt << 3) + threadIdx.x];
    }
    for (int t = threadIdx.x; t < 8 * 4 * 64; t += 512)
        ((float*)pool)[t] = 0.f;
    __syncthreads();

    // wave-parallel 8-aligned inclusive scan (wave 0); +1 slot for self
    if (threadIdx.x < 64) {
        int v = (threadIdx.x < nnodes) ? ((cnt[threadIdx.x] + 8) & ~7) : 0;
        int run = v;
#pragma unroll
        for (int off = 1; off < 64; off <<= 1) {
            int t = __shfl_up(run, off);
            if (threadIdx.x >= off) run += t;
        }
        lptr[threadIdx.x + 1] = run;
        if (threadIdx.x == 0) lptr[0] = 0;
    }
    __syncthreads();
    int tot = lptr[64]; if (tot > LDS_E2) tot = LDS_E2;
    for (int i = threadIdx.x; i < tot; i += 512) srt[i] = ZERO_ROW << 6;
    __syncthreads();
    // self slot (right after the node's edges) + per-graph node counts
    if (threadIdx.x < nnodes) {
        int p = lptr[threadIdx.x] + cnt[threadIdx.x];
        if (p < LDS_E2) srt[p] = (nbase + threadIdx.x) << 6;
        int sl = sb[threadIdx.x] - sb[0];
        if (sl < 8) atomicAdd(&gcl[sl], 1.0f);
        else atomicAdd(&gcnt[sb[threadIdx.x]], 1.0f);
    }
    for (int i = threadIdx.x; i < (1 << CAPSHIFT); i += 512) {  // CSR scatter
        if ((i & ((1 << SUBSHIFT) - 1)) < cnt8[i >> SUBSHIFT]) {
            int pk = binned[base + i];
            int nid = pk >> 17;
            int rk = atomicAdd(&cur[nid], 1);
            int pos = lptr[nid] + rk;
            if (pos < LDS_E2) srt[pos] = (pk & 0x1FFFF) << 6;   // byte offset
        }
    }
    __syncthreads();

    int wave = threadIdx.x >> 6;
    int lane = threadIdx.x & 63;
    int sub = lane >> 4;                // subset: owns one node at a time
    int lc  = lane & 15;                // lane-in-subset: cols 4lc..4lc+3
    int l4  = lc << 2;                  // byte offset of that dword in a row
    const unsigned char* xbl = xws + l4;
    int g0 = sb[0];
    float4 bia = ((const float4*)bg)[lc];

#pragma unroll
    for (int r = 0; r < 2; r++) {
        int ln = wave * 8 + sub * 2 + r;          // 32 processors x 2 rounds
        int valid = (ln < nnodes);
        int s0 = valid ? lptr[ln] : 0;
        int e0 = valid ? lptr[ln + 1] : 0;
        if (s0 > LDS_E2) s0 = LDS_E2;
        if (e0 > LDS_E2) e0 = LDS_E2;             // both multiples of 8
        f32x2 al0 = {0.f,0.f}, ah0 = {0.f,0.f};   // 4 independent chains
        f32x2 al1 = {0.f,0.f}, ah1 = {0.f,0.f};
        for (int i = s0; i < e0; i += 8) {        // divergent across subsets
            int4 ra = *(const int4*)&srt[i];      // subset-uniform broadcast
            int4 rb = *(const int4*)&srt[i + 4];
            unsigned int d0 = *(const unsigned int*)(xbl + ra.x);
            unsigned int d1 = *(const unsigned int*)(xbl + ra.y);
            unsigned int d2 = *(const unsigned int*)(xbl + ra.z);
            unsigned int d3 = *(const unsigned int*)(xbl + ra.w);
            unsigned int d4 = *(const unsigned int*)(xbl + rb.x);
            unsigned int d5 = *(const unsigned int*)(xbl + rb.y);
            unsigned int d6 = *(const unsigned int*)(xbl + rb.z);
            unsigned int d7 = *(const unsigned int*)(xbl + rb.w);
            f32x2 p;
            p = __builtin_amdgcn_cvt_pk_f32_fp8(d0, false); al0 += p;
            p = __builtin_amdgcn_cvt_pk_f32_fp8(d0, true);  ah0 += p;
            p = __builtin_amdgcn_cvt_pk_f32_fp8(d1, false); al1 += p;
            p = __builtin_amdgcn_cvt_pk_f32_fp8(d1, true);  ah1 += p;
            p = __builtin_amdgcn_cvt_pk_f32_fp8(d2, false); al0 += p;
            p = __builtin_amdgcn_cvt_pk_f32_fp8(d2, true);  ah0 += p;
            p = __builtin_amdgcn_cvt_pk_f32_fp8(d3, false); al1 += p;
            p = __builtin_amdgcn_cvt_pk_f32_fp8(d3, true);  ah1 += p;
            p = __builtin_amdgcn_cvt_pk_f32_fp8(d4, false); al0 += p;
            p = __builtin_amdgcn_cvt_pk_f32_fp8(d4, true);  ah0 += p;
            p = __builtin_amdgcn_cvt_pk_f32_fp8(d5, false); al1 += p;
            p = __builtin_amdgcn_cvt_pk_f32_fp8(d5, true);  ah1 += p;
            p = __builtin_amdgcn_cvt_pk_f32_fp8(d6, false); al0 += p;
            p = __builtin_amdgcn_cvt_pk_f32_fp8(d6, true);  ah0 += p;
            p = __builtin_amdgcn_cvt_pk_f32_fp8(d7, false); al1 += p;
            p = __builtin_amdgcn_cvt_pk_f32_fp8(d7, true);  ah1 += p;
        }
        f32x2 alo = al0 + al1, ahi = ah0 + ah1;
        int slot = 99;
        float4 val;
        if (valid) {
            float dn = rsqrtf((float)cnt[ln] + 1.0f);
            val.x = fmaxf(alo[0] * dn + bia.x, 0.f);
            val.y = fmaxf(alo[1] * dn + bia.y, 0.f);
            val.z = fmaxf(ahi[0] * dn + bia.z, 0.f);
            val.w = fmaxf(ahi[1] * dn + bia.w, 0.f);
            slot = sb[ln] - g0;
        }
        // serialize the 4 subsets' pool RMW (same wave -> in-order LDS ops)
#pragma unroll
        for (int ss = 0; ss < 4; ss++) {
            if (sub == ss && slot < 4) {
                float4* pp = (float4*)&pool[wave][slot][l4];
                float4 pv = *pp;
                pv.x += val.x; pv.y += val.y; pv.z += val.z; pv.w += val.w;
                *pp = pv;
            }
        }
        if (slot >= 4 && slot < 99) {             // rare: >4 graphs in window
            float* gp = &gsum[sb[ln] * HID_DIM + l4];
            atomicAdd(gp + 0, val.x); atomicAdd(gp + 1, val.y);
            atomicAdd(gp + 2, val.z); atomicAdd(gp + 3, val.w);
        }
    }
    __syncthreads();

    if (threadIdx.x < 8) {
        float c = gcl[threadIdx.x];
        if (c != 0.f) atomicAdd(&gcnt[g0 + threadIdx.x], c);
    }
    for (int t = threadIdx.x; t < 4 * 64; t += 512) {
        int slot = t >> 6, j = t & 63;
        float v = 0.f;
#pragma unroll
        for (int w2 = 0; w2 < 8; w2++) v += pool[w2][slot][j];
        if (v != 0.f) atomicAdd(&gsum[(g0 + slot) * HID_DIM + j], v);
    }
}

// ---- divide by counts + MLP + sigmoid (one wave per graph) ---------------
__global__ __launch_bounds__(64) void k_mlp(const float* __restrict__ gsum,
                                            const float* __restrict__ gcnt,
                                            const float* __restrict__ W1,
                                            const float* __restrict__ b1,
                                            const float* __restrict__ W2,
                                            const float* __restrict__ b2,
                                            float* __restrict__ out) {
    int g = blockIdx.x;
    int j = threadIdx.x;
    float cnt = fmaxf(gcnt[g], 1.0f);

    __shared__ float gs[64];
    __shared__ float hs[64];
    gs[j] = gsum[g * 64 + j] / cnt;
    __syncthreads();

    float h = b1[j];
    for (int k = 0; k < 64; k++) h += gs[k] * W1[k * 64 + j];
    hs[j] = fmaxf(h, 0.f);
    __syncthreads();

    if (j < OUT_DIM) {
        float o = b2[j];
        for (int k = 0; k < 64; k++) o += hs[k] * W2[k * OUT_DIM + j];
        out[g * OUT_DIM + j] = 1.f / (1.f + expf(-o));
    }
}

extern "C" void kernel_launch(void* const* d_in, const int* in_sizes, int n_in,
                              void* d_out, int out_size, void* d_ws, size_t ws_size,
                              hipStream_t stream) {
    const float* x   = (const float*)d_in[0];
    const int* eidx  = (const int*)d_in[1];
    const int* batch = (const int*)d_in[2];
    const float* Wg  = (const float*)d_in[3];
    const float* bg  = (const float*)d_in[4];
    const float* W1  = (const float*)d_in[5];
    const float* b1  = (const float*)d_in[6];
    const float* W2  = (const float*)d_in[7];
    const float* b2  = (const float*)d_in[8];
    float* out = (float*)d_out;

    // workspace layout (~32.7 MB)
    char* w = (char*)d_ws;
    unsigned char* xws = (unsigned char*)w;     w += (size_t)(N_NODES + 1) * HID_DIM;    // 6.4 MB (fp8)
    int*   binned  = (int*)w;                   w += ((size_t)NBK << CAPSHIFT) * 4;      // 25.6 MB fixed-stride
    int*   cnt_g   = (int*)w;                   w += (size_t)NBK * 8 * 4;                // 50 KB sub-counters
    int*   degs    = (int*)w;                   w += (size_t)NBK * 64 * 4;               // 400 KB
    float* gsum    = (float*)w;                 w += N_GRAPHS * HID_DIM * 4;             // 131 KB
    float* gcnt    = (float*)w;                 w += N_GRAPHS * 4;                       // 2 KB

    const int* rowp = eidx;             // edge_index[0] (sources)
    const int* colp = eidx + N_EDGES;   // edge_index[1] (destinations)

    k_init<<<46, 1024, 0, stream>>>(gsum, cnt_g, gcnt, xws);
    k_bin<<<NBB, 512, 0, stream>>>(rowp, colp, cnt_g, binned);
    k_gemm<<<NBK, 256, 0, stream>>>(x, Wg, cnt_g, binned, degs, xws);
    k_aggrf<<<NBK, 512, 0, stream>>>(xws, binned, cnt_g, degs, batch, bg, gsum, gcnt);
    k_mlp<<<N_GRAPHS, 64, 0, stream>>>(gsum, gcnt, W1, b1, W2, b2, out);
}

// Round 11
// 210.473 us; speedup vs baseline: 1.1502x; 1.1502x over previous
//
#include <hip/hip_runtime.h>

#define N_NODES 100000
#define N_EDGES 3200000
#define IN_DIM 128
#define HID_DIM 64
#define OUT_DIM 2
#define N_GRAPHS 512

#define BSHIFT 6
#define NBK 1563           // ceil(100000/64) fine buckets of 64 nodes
#define NSUP 98            // super-buckets of 1024 nodes (2-level radix)
#define SUPCAP 36864       // slots per super (mean 32.7K, +23 sd)
#define NBS 512            // super-pass blocks
#define EPS 6250           // edges per super-pass block (512*6250 = 3.2M)
#define CAPSHIFT 12        // 4096 slots per fine bucket (max ~2300)
#define LDS_E2 2816        // per-bucket LDS edge capacity in aggrf (8-aligned + self)
#define ZERO_ROW N_NODES   // all-zero fp8 row used for alignment padding

__device__ inline unsigned short f2bf(float f) {
    union { float f; unsigned int i; } v; v.f = f;
    unsigned int r = v.i + 0x7fffu + ((v.i >> 16) & 1u);
    return (unsigned short)(r >> 16);
}

typedef __attribute__((ext_vector_type(8))) short bf16x8;
typedef __attribute__((ext_vector_type(4))) float f32x4;
typedef __attribute__((ext_vector_type(2))) float f32x2;

// ---- pass 0: zero scnt/cnt_g/gsum/gcnt + ZERO_ROW ------------------------
__global__ __launch_bounds__(1024) void k_init(float* __restrict__ gsum,
                                               int* __restrict__ cnt_g,
                                               int* __restrict__ scnt,
                                               float* __restrict__ gcnt,
                                               unsigned char* __restrict__ xws) {
    int b = blockIdx.x, t = threadIdx.x;
    if (b < 32) {
        gsum[b * 1024 + t] = 0.f;                     // 32768 floats
    } else if (b == 32) {
        cnt_g[t] = 0;                                 // 0..1023
    } else if (b == 33) {
        if (t < NBK - 1024) cnt_g[1024 + t] = 0;      // 1024..1562
        if (t >= 600 && t < 600 + NSUP) scnt[t - 600] = 0;
    } else {
        if (t < N_GRAPHS) gcnt[t] = 0.f;
        if (t >= 1008)
            ((int*)(xws + (size_t)ZERO_ROW * HID_DIM))[t - 1008] = 0;
    }
}

// ---- pass 1a: sort into 98 SUPER-buckets (1024 nodes each) ---------------
// Two-level radix beats one-level: per-(block,super) runs are mean 64
// edges = 256B -> near-perfect write coalescing (R10 lesson: per-wave
// write-TRANSACTION count, not bytes, dominates scatter cost; one-level
// 1563-bucket runs were 8-16B). LDS stages only 16-bit edge indices
// (13.7 KB total -> grid 512 = 16 waves/CU). Edge packs into 4B:
// pk1 = (c & 1023) << 17 | r  (c-within-super 10b, row 17b).
__global__ __launch_bounds__(512) void k_super(const int* __restrict__ row,
                                               const int* __restrict__ col,
                                               int* __restrict__ scnt,
                                               int* __restrict__ sup) {
    __shared__ int h[NSUP];            // count -> global run base
    __shared__ int cur[NSUP];
    __shared__ int lofs[NSUP + 1];
    __shared__ unsigned short idx16[EPS];   // 12.5 KB staged edge indices
    int t = threadIdx.x;
    if (t < NSUP) { h[t] = 0; cur[t] = 0; }
    __syncthreads();
    int s = blockIdx.x * EPS;
    for (int i = t; i < EPS; i += 512)
        atomicAdd(&h[col[s + i] >> 10], 1);
    __syncthreads();
    if (t == 0) {                      // tiny serial scan (98 entries)
        int run = 0;
        for (int i = 0; i < NSUP; i++) { lofs[i] = run; run += h[i]; }
        lofs[NSUP] = run;
    }
    __syncthreads();
    if (t < NSUP) {                    // reserve global run
        int hv = h[t];
        if (hv) h[t] = t * SUPCAP + atomicAdd(&scnt[t], hv);
    }
    __syncthreads();
    for (int i = t; i < EPS; i += 512) {    // LDS scatter of indices
        int sb = col[s + i] >> 10;
        int rk = atomicAdd(&cur[sb], 1);
        idx16[lofs[sb] + rk] = (unsigned short)i;
    }
    __syncthreads();
    // coalesced copy-out (col/row gathers hit the block's L1/L2 window)
    for (int i = t; i < EPS; i += 512) {
        int idx = idx16[i];
        int c = col[s + idx];
        int r = row[s + idx];
        int sb = c >> 10;
        sup[h[sb] + (i - lofs[sb])] = ((c & 1023) << 17) | r;
    }
}

// ---- pass 1b: sort each super-bucket into its 16 FINE buckets ------------
// 4 blocks per super, each takes a quarter of the super's edges (L2/L3-
// hot). Fine buckets are OWNED by one super -> runs of mean ~512 edges,
// fully coalesced, written dense from slot 0 of binned[fb<<12] (consumers
// use simple m = cnt_g[fb]). fine-in-super = bits [26:23] of pk1; final
// pk = pk1 & 0x7FFFFF keeps (c&63)<<17 | r.
__global__ __launch_bounds__(512) void k_fine(const int* __restrict__ sup,
                                              const int* __restrict__ scnt,
                                              int* __restrict__ cnt_g,
                                              int* __restrict__ binned) {
    __shared__ int h[16];
    __shared__ int cur[16];
    __shared__ int lofs[17];
    __shared__ int resv[16];
    __shared__ unsigned short idx16[9216];  // 18 KB (quarter <= ~8400)
    int sb = blockIdx.x >> 2, q = blockIdx.x & 3;
    int m = scnt[sb]; if (m > SUPCAP) m = SUPCAP;
    int qs = (q * m) >> 2, qe = ((q + 1) * m) >> 2;
    int n = qe - qs; if (n > 9216) n = 9216;
    int base = sb * SUPCAP + qs;
    int t = threadIdx.x;
    if (t < 16) { h[t] = 0; cur[t] = 0; }
    __syncthreads();
    for (int i = t; i < n; i += 512)
        atomicAdd(&h[(sup[base + i] >> 23) & 15], 1);
    __syncthreads();
    if (t == 0) {
        int run = 0;
        for (int i = 0; i < 16; i++) { lofs[i] = run; run += h[i]; }
        lofs[16] = run;
    }
    __syncthreads();
    if (t < 16) {
        int hv = h[t];
        int fb = (sb << 4) + t;
        resv[t] = (hv && fb < NBK) ? (fb << CAPSHIFT) + atomicAdd(&cnt_g[fb], hv) : 0;
    }
    __syncthreads();
    for (int i = t; i < n; i += 512) {
        int fbl = (sup[base + i] >> 23) & 15;
        int rk = atomicAdd(&cur[fbl], 1);
        idx16[lofs[fbl] + rk] = (unsigned short)i;
    }
    __syncthreads();
    for (int i = t; i < n; i += 512) {      // coalesced copy-out
        int pk1 = sup[base + idx16[i]];
        int fbl = (pk1 >> 23) & 15;
        binned[resv[fbl] + (i - lofs[fbl])] = pk1 & 0x7FFFFF;
    }
}

// ---- xws = (x @ W_gcn) * dinv via MFMA, output fp8 e4m3 ------------------
// Block == bucket: degree hist fused (k_deg deleted); dense binned slots
// 0..m (R6-verified indexing). Hist global loads + LDS atomics issue
// BEFORE the MFMA loop and complete under it. cnt spills to degs[] for
// k_aggrf. Wave does a 16-node x 64-col tile with mfma_f32_16x16x32_bf16;
// C/D: col=lane&15, row=quad*4+reg.
__global__ __launch_bounds__(256) void k_gemm(const float* __restrict__ x,
                                              const float* __restrict__ Wg,
                                              const int* __restrict__ cnt_g,
                                              const int* __restrict__ binned,
                                              int* __restrict__ degs,
                                              unsigned char* __restrict__ xws) {
    __shared__ unsigned short wb[16][64][8];   // [ks*4+nt][lane][j]  16 KB
    __shared__ int cnt[64];

    if (threadIdx.x < 64) cnt[threadIdx.x] = 0;
    for (int idx = threadIdx.x; idx < 1024; idx += 256) {
        int f = idx >> 6, l = idx & 63;
        int ks = f >> 2, nt = f & 3;
        int n = (l & 15) + (nt << 4);
        int kbase = (ks << 5) + ((l >> 4) << 3);
        unsigned short tmp[8];
#pragma unroll
        for (int j = 0; j < 8; j++)
            tmp[j] = f2bf(Wg[(kbase + j) * HID_DIM + n]);
        *(bf16x8*)&wb[f][l][0] = *(const bf16x8*)tmp;
    }
    __syncthreads();

    int bkt = blockIdx.x;
    int m = cnt_g[bkt];
    for (int i = threadIdx.x; i < m; i += 256)          // deg hist (overlaps MFMA)
        atomicAdd(&cnt[binned[(bkt << CAPSHIFT) + i] >> 17], 1);

    int wave = threadIdx.x >> 6;
    int lane = threadIdx.x & 63;
    int q = lane >> 4, nn = lane & 15;

    bf16x8 bfrag[4][4];
#pragma unroll
    for (int ks = 0; ks < 4; ks++)
#pragma unroll
        for (int nt = 0; nt < 4; nt++)
            bfrag[ks][nt] = *(const bf16x8*)&wb[ks * 4 + nt][lane][0];

    int node0 = bkt * 64 + wave * 16;
    int arow = node0 + nn;
    if (arow > N_NODES - 1) arow = N_NODES - 1;   // clamp (stores predicated)
    const float* xrow = x + (size_t)arow * IN_DIM + (q << 3);

    f32x4 acc[4] = {{0.f,0.f,0.f,0.f},{0.f,0.f,0.f,0.f},
                    {0.f,0.f,0.f,0.f},{0.f,0.f,0.f,0.f}};
#pragma unroll
    for (int ks = 0; ks < 4; ks++) {
        float4 xa = *(const float4*)(xrow + ks * 32);
        float4 xb_ = *(const float4*)(xrow + ks * 32 + 4);
        bf16x8 af;
        af[0] = (short)f2bf(xa.x); af[1] = (short)f2bf(xa.y);
        af[2] = (short)f2bf(xa.z); af[3] = (short)f2bf(xa.w);
        af[4] = (short)f2bf(xb_.x); af[5] = (short)f2bf(xb_.y);
        af[6] = (short)f2bf(xb_.z); af[7] = (short)f2bf(xb_.w);
#pragma unroll
        for (int nt = 0; nt < 4; nt++)
            acc[nt] = __builtin_amdgcn_mfma_f32_16x16x32_bf16(af, bfrag[ks][nt], acc[nt], 0, 0, 0);
    }
    __syncthreads();                                    // cnt hist complete

    if (threadIdx.x < 64) degs[bkt * 64 + threadIdx.x] = cnt[threadIdx.x];

#pragma unroll
    for (int r = 0; r < 4; r++) {
        int lrow = wave * 16 + q * 4 + r;
        int mrow = bkt * 64 + lrow;
        if (mrow < N_NODES) {
            float dn = rsqrtf((float)cnt[lrow] + 1.0f);
            int p01 = __builtin_amdgcn_cvt_pk_fp8_f32(acc[0][r] * dn, acc[1][r] * dn, 0, false);
            int p23 = __builtin_amdgcn_cvt_pk_fp8_f32(acc[2][r] * dn, acc[3][r] * dn, 0, false);
            unsigned char* rp = xws + (size_t)mrow * HID_DIM + nn;
            rp[0]  = (unsigned char)(p01 & 0xff);
            rp[16] = (unsigned char)((p01 >> 8) & 0xff);
            rp[32] = (unsigned char)(p23 & 0xff);
            rp[48] = (unsigned char)((p23 >> 8) & 0xff);
        }
    }
}

// ---- fused local-CSR build + gather-aggregate + ReLU + mean-pool ---------
// 512-thread block per 64-node bucket. Degrees come from degs[] (k_gemm);
// dense binned slots 0..m. srt holds BYTE offsets (row<<6). Subset-per-
// node gather: each 16-lane subset owns ONE node end-to-end -> zero-
// shuffle epilogue. Lists 8-aligned with self-loop folded in; 8 slots/iter
// (2x ds_read_b128 + 8 row-loads in flight) with 4 independent accumulator
// chains. Per-graph node counts (gcnt) accumulated here.
__global__ __launch_bounds__(512) void k_aggrf(const unsigned char* __restrict__ xws,
                                               const int* __restrict__ binned,
                                               const int* __restrict__ cnt_g,
                                               const int* __restrict__ degs,
                                               const int* __restrict__ batch,
                                               const float* __restrict__ bg,
                                               float* __restrict__ gsum,
                                               float* __restrict__ gcnt) {
    int bkt = blockIdx.x;
    int nbase = bkt << BSHIFT;
    int nnodes = N_NODES - nbase; if (nnodes > 64) nnodes = 64;
    int m = cnt_g[bkt];
    int base = bkt << CAPSHIFT;

    __shared__ int cnt[64];
    __shared__ int lptr[65];
    __shared__ int cur[64];
    __shared__ int sb[64];
    __shared__ float gcl[8];
    __shared__ alignas(16) int srt[LDS_E2];
    __shared__ float pool[8][4][64];   // [wave][graph-slot][col]

    if (threadIdx.x < 64) {
        int n = nbase + threadIdx.x;
        cnt[threadIdx.x] = (threadIdx.x < nnodes) ? degs[bkt * 64 + threadIdx.x] : 0;
        sb[threadIdx.x]  = (threadIdx.x < nnodes) ? batch[n] : 0;
        cur[threadIdx.x] = 0;
    }
    if (threadIdx.x < 8) gcl[threadIdx.x] = 0.f;
    for (int t = threadIdx.x; t < 8 * 4 * 64; t += 512)
        ((float*)pool)[t] = 0.f;
    __syncthreads();

    // wave-parallel 8-aligned inclusive scan (wave 0); +1 slot for self
    if (threadIdx.x < 64) {
        int v = (threadIdx.x < nnodes) ? ((cnt[threadIdx.x] + 8) & ~7) : 0;
        int run = v;
#pragma unroll
        for (int off = 1; off < 64; off <<= 1) {
            int t = __shfl_up(run, off);
            if (threadIdx.x >= off) run += t;
        }
        lptr[threadIdx.x + 1] = run;
        if (threadIdx.x == 0) lptr[0] = 0;
    }
    __syncthreads();
    int tot = lptr[64]; if (tot > LDS_E2) tot = LDS_E2;
    for (int i = threadIdx.x; i < tot; i += 512) srt[i] = ZERO_ROW << 6;
    __syncthreads();
    // self slot (right after the node's edges) + per-graph node counts
    if (threadIdx.x < nnodes) {
        int p = lptr[threadIdx.x] + cnt[threadIdx.x];
        if (p < LDS_E2) srt[p] = (nbase + threadIdx.x) << 6;
        int sl = sb[threadIdx.x] - sb[0];
        if (sl < 8) atomicAdd(&gcl[sl], 1.0f);
        else atomicAdd(&gcnt[sb[threadIdx.x]], 1.0f);
    }
    for (int i = threadIdx.x; i < m; i += 512) {        // CSR scatter
        int pk = binned[base + i];
        int nid = pk >> 17;
        int rk = atomicAdd(&cur[nid], 1);
        int pos = lptr[nid] + rk;
        if (pos < LDS_E2) srt[pos] = (pk & 0x1FFFF) << 6;   // byte offset
    }
    __syncthreads();

    int wave = threadIdx.x >> 6;
    int lane = threadIdx.x & 63;
    int sub = lane >> 4;                // subset: owns one node at a time
    int lc  = lane & 15;                // lane-in-subset: cols 4lc..4lc+3
    int l4  = lc << 2;                  // byte offset of that dword in a row
    const unsigned char* xbl = xws + l4;
    int g0 = sb[0];
    float4 bia = ((const float4*)bg)[lc];

#pragma unroll
    for (int r = 0; r < 2; r++) {
        int ln = wave * 8 + sub * 2 + r;          // 32 processors x 2 rounds
        int valid = (ln < nnodes);
        int s0 = valid ? lptr[ln] : 0;
        int e0 = valid ? lptr[ln + 1] : 0;
        if (s0 > LDS_E2) s0 = LDS_E2;
        if (e0 > LDS_E2) e0 = LDS_E2;             // both multiples of 8
        f32x2 al0 = {0.f,0.f}, ah0 = {0.f,0.f};   // 4 independent chains
        f32x2 al1 = {0.f,0.f}, ah1 = {0.f,0.f};
        for (int i = s0; i < e0; i += 8) {        // divergent across subsets
            int4 ra = *(const int4*)&srt[i];      // subset-uniform broadcast
            int4 rb = *(const int4*)&srt[i + 4];
            unsigned int d0 = *(const unsigned int*)(xbl + ra.x);
            unsigned int d1 = *(const unsigned int*)(xbl + ra.y);
            unsigned int d2 = *(const unsigned int*)(xbl + ra.z);
            unsigned int d3 = *(const unsigned int*)(xbl + ra.w);
            unsigned int d4 = *(const unsigned int*)(xbl + rb.x);
            unsigned int d5 = *(const unsigned int*)(xbl + rb.y);
            unsigned int d6 = *(const unsigned int*)(xbl + rb.z);
            unsigned int d7 = *(const unsigned int*)(xbl + rb.w);
            f32x2 p;
            p = __builtin_amdgcn_cvt_pk_f32_fp8(d0, false); al0 += p;
            p = __builtin_amdgcn_cvt_pk_f32_fp8(d0, true);  ah0 += p;
            p = __builtin_amdgcn_cvt_pk_f32_fp8(d1, false); al1 += p;
            p = __builtin_amdgcn_cvt_pk_f32_fp8(d1, true);  ah1 += p;
            p = __builtin_amdgcn_cvt_pk_f32_fp8(d2, false); al0 += p;
            p = __builtin_amdgcn_cvt_pk_f32_fp8(d2, true);  ah0 += p;
            p = __builtin_amdgcn_cvt_pk_f32_fp8(d3, false); al1 += p;
            p = __builtin_amdgcn_cvt_pk_f32_fp8(d3, true);  ah1 += p;
            p = __builtin_amdgcn_cvt_pk_f32_fp8(d4, false); al0 += p;
            p = __builtin_amdgcn_cvt_pk_f32_fp8(d4, true);  ah0 += p;
            p = __builtin_amdgcn_cvt_pk_f32_fp8(d5, false); al1 += p;
            p = __builtin_amdgcn_cvt_pk_f32_fp8(d5, true);  ah1 += p;
            p = __builtin_amdgcn_cvt_pk_f32_fp8(d6, false); al0 += p;
            p = __builtin_amdgcn_cvt_pk_f32_fp8(d6, true);  ah0 += p;
            p = __builtin_amdgcn_cvt_pk_f32_fp8(d7, false); al1 += p;
            p = __builtin_amdgcn_cvt_pk_f32_fp8(d7, true);  ah1 += p;
        }
        f32x2 alo = al0 + al1, ahi = ah0 + ah1;
        int slot = 99;
        float4 val;
        if (valid) {
            float dn = rsqrtf((float)cnt[ln] + 1.0f);
            val.x = fmaxf(alo[0] * dn + bia.x, 0.f);
            val.y = fmaxf(alo[1] * dn + bia.y, 0.f);
            val.z = fmaxf(ahi[0] * dn + bia.z, 0.f);
            val.w = fmaxf(ahi[1] * dn + bia.w, 0.f);
            slot = sb[ln] - g0;
        }
        // serialize the 4 subsets' pool RMW (same wave -> in-order LDS ops)
#pragma unroll
        for (int ss = 0; ss < 4; ss++) {
            if (sub == ss && slot < 4) {
                float4* pp = (float4*)&pool[wave][slot][l4];
                float4 pv = *pp;
                pv.x += val.x; pv.y += val.y; pv.z += val.z; pv.w += val.w;
                *pp = pv;
            }
        }
        if (slot >= 4 && slot < 99) {             // rare: >4 graphs in window
            float* gp = &gsum[sb[ln] * HID_DIM + l4];
            atomicAdd(gp + 0, val.x); atomicAdd(gp + 1, val.y);
            atomicAdd(gp + 2, val.z); atomicAdd(gp + 3, val.w);
        }
    }
    __syncthreads();

    if (threadIdx.x < 8) {
        float c = gcl[threadIdx.x];
        if (c != 0.f) atomicAdd(&gcnt[g0 + threadIdx.x], c);
    }
    for (int t = threadIdx.x; t < 4 * 64; t += 512) {
        int slot = t >> 6, j = t & 63;
        float v = 0.f;
#pragma unroll
        for (int w2 = 0; w2 < 8; w2++) v += pool[w2][slot][j];
        if (v != 0.f) atomicAdd(&gsum[(g0 + slot) * HID_DIM + j], v);
    }
}

// ---- divide by counts + MLP + sigmoid (one wave per graph) ---------------
__global__ __launch_bounds__(64) void k_mlp(const float* __restrict__ gsum,
                                            const float* __restrict__ gcnt,
                                            const float* __restrict__ W1,
                                            const float* __restrict__ b1,
                                            const float* __restrict__ W2,
                                            const float* __restrict__ b2,
                                            float* __restrict__ out) {
    int g = blockIdx.x;
    int j = threadIdx.x;
    float cnt = fmaxf(gcnt[g], 1.0f);

    __shared__ float gs[64];
    __shared__ float hs[64];
    gs[j] = gsum[g * 64 + j] / cnt;
    __syncthreads();

    float h = b1[j];
    for (int k = 0; k < 64; k++) h += gs[k] * W1[k * 64 + j];
    hs[j] = fmaxf(h, 0.f);
    __syncthreads();

    if (j < OUT_DIM) {
        float o = b2[j];
        for (int k = 0; k < 64; k++) o += hs[k] * W2[k * OUT_DIM + j];
        out[g * OUT_DIM + j] = 1.f / (1.f + expf(-o));
    }
}

extern "C" void kernel_launch(void* const* d_in, const int* in_sizes, int n_in,
                              void* d_out, int out_size, void* d_ws, size_t ws_size,
                              hipStream_t stream) {
    const float* x   = (const float*)d_in[0];
    const int* eidx  = (const int*)d_in[1];
    const int* batch = (const int*)d_in[2];
    const float* Wg  = (const float*)d_in[3];
    const float* bg  = (const float*)d_in[4];
    const float* W1  = (const float*)d_in[5];
    const float* b1  = (const float*)d_in[6];
    const float* W2  = (const float*)d_in[7];
    const float* b2  = (const float*)d_in[8];
    float* out = (float*)d_out;

    // workspace layout (~47.3 MB)
    char* w = (char*)d_ws;
    unsigned char* xws = (unsigned char*)w;     w += (size_t)(N_NODES + 1) * HID_DIM;    // 6.4 MB (fp8)
    int*   sup     = (int*)w;                   w += (size_t)(NSUP + 1) * SUPCAP * 4;    // 14.6 MB (+1 slack)
    int*   binned  = (int*)w;                   w += ((size_t)NBK << CAPSHIFT) * 4;      // 25.6 MB
    int*   scnt    = (int*)w;                   w += NSUP * 4;
    int*   cnt_g   = (int*)w;                   w += NBK * 4;
    int*   degs    = (int*)w;                   w += (size_t)NBK * 64 * 4;               // 400 KB
    float* gsum    = (float*)w;                 w += N_GRAPHS * HID_DIM * 4;             // 131 KB
    float* gcnt    = (float*)w;                 w += N_GRAPHS * 4;                       // 2 KB

    const int* rowp = eidx;             // edge_index[0] (sources)
    const int* colp = eidx + N_EDGES;   // edge_index[1] (destinations)

    k_init<<<35, 1024, 0, stream>>>(gsum, cnt_g, scnt, gcnt, xws);
    k_super<<<NBS, 512, 0, stream>>>(rowp, colp, scnt, sup);
    k_fine<<<NSUP * 4, 512, 0, stream>>>(sup, scnt, cnt_g, binned);
    k_gemm<<<NBK, 256, 0, stream>>>(x, Wg, cnt_g, binned, degs, xws);
    k_aggrf<<<NBK, 512, 0, stream>>>(xws, binned, cnt_g, degs, batch, bg, gsum, gcnt);
    k_mlp<<<N_GRAPHS, 64, 0, stream>>>(gsum, gcnt, W1, b1, W2, b2, out);
}